// Round 1
// baseline (906.417 us; speedup 1.0000x reference)
//
#include <hip/hip_runtime.h>

typedef __bf16 bf16x8 __attribute__((ext_vector_type(8)));
typedef unsigned short u16x8 __attribute__((ext_vector_type(8)));
typedef float f32x4 __attribute__((ext_vector_type(4)));

// sizes: B=16, S=1024, D=512, T=3, BT=48
// Xb/Qb/Kb layout: [bt][s][d] bf16 ; Vt layout: [bt][d][s] bf16

__device__ __forceinline__ unsigned short f2bf(float x){
  unsigned u = __float_as_uint(x);
  u += 0x7fffu + ((u >> 16) & 1u);
  return (unsigned short)(u >> 16);
}

// ---------- convert features fp32 -> bf16, stacked [48][1024][512] ----------
__global__ void k_conv_feat(const float* __restrict__ f0, const float* __restrict__ f1,
                            const float* __restrict__ f2, unsigned short* __restrict__ Xb){
  size_t i = (size_t)blockIdx.x * blockDim.x + threadIdx.x;   // one 8-elem chunk
  size_t e = i * 8;
  size_t bt = e >> 19;                 // / (1024*512)
  size_t rest = e & ((1u << 19) - 1);
  int b = (int)(bt / 3), t = (int)(bt % 3);
  const float* src = (t == 0 ? f0 : (t == 1 ? f1 : f2)) + ((size_t)b << 19) + rest;
  f32x4 v0 = *(const f32x4*)(src);
  f32x4 v1 = *(const f32x4*)(src + 4);
  u16x8 o;
  o[0] = f2bf(v0[0]); o[1] = f2bf(v0[1]); o[2] = f2bf(v0[2]); o[3] = f2bf(v0[3]);
  o[4] = f2bf(v1[0]); o[5] = f2bf(v1[1]); o[6] = f2bf(v1[2]); o[7] = f2bf(v1[3]);
  *(u16x8*)(Xb + e) = o;
}

// ---------- convert weights fp32 -> bf16, Wb = [Wq|Wk|Wv] each [512][512] ----------
__global__ void k_conv_w(const float* __restrict__ wq, const float* __restrict__ wk,
                         const float* __restrict__ wv, unsigned short* __restrict__ Wb){
  size_t i = (size_t)blockIdx.x * blockDim.x + threadIdx.x;
  size_t e = i * 8;
  int sel = (int)(e >> 18);            // 262144 elems per matrix
  size_t rest = e & ((1u << 18) - 1);
  const float* src = (sel == 0 ? wq : (sel == 1 ? wk : wv)) + rest;
  f32x4 v0 = *(const f32x4*)(src);
  f32x4 v1 = *(const f32x4*)(src + 4);
  u16x8 o;
  o[0] = f2bf(v0[0]); o[1] = f2bf(v0[1]); o[2] = f2bf(v0[2]); o[3] = f2bf(v0[3]);
  o[4] = f2bf(v1[0]); o[5] = f2bf(v1[1]); o[6] = f2bf(v1[2]); o[7] = f2bf(v1[3]);
  *(u16x8*)(Wb + e) = o;
}

// ---------- C = A * B^T (+bias), bf16 in/out, fp32 accum. K = 512 fixed. ----------
// MODE 0: C[m][n] at m*N+n, bias[n]   (Q, K projections; m = bt*1024+s, n = e)
// MODE 1: C[m][n] at (n>>10)*2^19 + m*1024 + (n&1023), bias[m]   (Vt: m = e, n = bt*1024+s)
template<int MODE>
__global__ __launch_bounds__(256, 2)
void k_gemm_bt(const unsigned short* __restrict__ A, const unsigned short* __restrict__ Bm,
               const float* __restrict__ bias, unsigned short* __restrict__ C, int N){
  __shared__ unsigned short Al[2][128 * 64];
  __shared__ unsigned short Bl[2][128 * 64];
  const int tid = threadIdx.x;
  const int l  = tid & 63;
  const int wid = tid >> 6;
  const int lr = l & 15;     // frag row/col within 16
  const int lg = l >> 4;     // k-group 0..3
  const int nbc = N >> 7;
  const int rb = blockIdx.x / nbc;
  const int cb = blockIdx.x % nbc;
  const unsigned short* Ab = A + (size_t)rb * 128 * 512;
  const unsigned short* Bb = Bm + (size_t)cb * 128 * 512;

  const f32x4 zero4 = {0.f, 0.f, 0.f, 0.f};
  f32x4 acc[4][4];
  #pragma unroll
  for (int i = 0; i < 4; ++i)
    #pragma unroll
    for (int j = 0; j < 4; ++j) acc[i][j] = zero4;

  // stage k-tile 0 (chunk-XOR swizzle: chunk c of row r stored at c^(r&7))
  {
    u16x8 va[4], vb[4];
    #pragma unroll
    for (int i = 0; i < 4; ++i){
      int j = i * 256 + tid; int r = j >> 3, c = j & 7;
      va[i] = *(const u16x8*)(Ab + (size_t)r * 512 + c * 8);
      vb[i] = *(const u16x8*)(Bb + (size_t)r * 512 + c * 8);
    }
    #pragma unroll
    for (int i = 0; i < 4; ++i){
      int j = i * 256 + tid; int r = j >> 3, c = j & 7;
      int cc = c ^ (r & 7);
      *(u16x8*)(&Al[0][(r << 6) + (cc << 3)]) = va[i];
      *(u16x8*)(&Bl[0][(r << 6) + (cc << 3)]) = vb[i];
    }
  }
  __syncthreads();

  const int wr = wid >> 1, wc = wid & 1;

  for (int kb = 0; kb < 8; ++kb){
    const int cur = kb & 1;
    u16x8 va[4], vb[4];
    if (kb < 7){
      #pragma unroll
      for (int i = 0; i < 4; ++i){
        int j = i * 256 + tid; int r = j >> 3, c = j & 7;
        va[i] = *(const u16x8*)(Ab + (size_t)r * 512 + (kb + 1) * 64 + c * 8);
        vb[i] = *(const u16x8*)(Bb + (size_t)r * 512 + (kb + 1) * 64 + c * 8);
      }
    }
    #pragma unroll
    for (int ks = 0; ks < 2; ++ks){
      bf16x8 af[4], bf[4];
      #pragma unroll
      for (int i = 0; i < 4; ++i){
        int row = wr * 64 + i * 16 + lr;
        int ch = (ks * 4 + lg) ^ (row & 7);
        af[i] = *(const bf16x8*)(&Al[cur][(row << 6) + (ch << 3)]);
      }
      #pragma unroll
      for (int j = 0; j < 4; ++j){
        int row = wc * 64 + j * 16 + lr;
        int ch = (ks * 4 + lg) ^ (row & 7);
        bf[j] = *(const bf16x8*)(&Bl[cur][(row << 6) + (ch << 3)]);
      }
      #pragma unroll
      for (int i = 0; i < 4; ++i)
        #pragma unroll
        for (int j = 0; j < 4; ++j)
          acc[i][j] = __builtin_amdgcn_mfma_f32_16x16x32_bf16(af[i], bf[j], acc[i][j], 0, 0, 0);
    }
    __syncthreads();
    if (kb < 7){
      #pragma unroll
      for (int i = 0; i < 4; ++i){
        int j = i * 256 + tid; int r = j >> 3, c = j & 7;
        int cc = c ^ (r & 7);
        *(u16x8*)(&Al[cur ^ 1][(r << 6) + (cc << 3)]) = va[i];
        *(u16x8*)(&Bl[cur ^ 1][(r << 6) + (cc << 3)]) = vb[i];
      }
      __syncthreads();
    }
  }

  // epilogue: D layout col = lane&15, row = (lane>>4)*4 + reg
  #pragma unroll
  for (int j = 0; j < 4; ++j){
    int col = cb * 128 + wc * 64 + j * 16 + lr;
    float bc = (MODE == 0) ? bias[col] : 0.f;
    #pragma unroll
    for (int i = 0; i < 4; ++i){
      int row0 = rb * 128 + wr * 64 + i * 16 + lg * 4;
      #pragma unroll
      for (int r = 0; r < 4; ++r){
        int row = row0 + r;
        float v = acc[i][j][r] + ((MODE == 0) ? bc : bias[row]);
        size_t addr;
        if (MODE == 0) addr = (size_t)row * N + col;
        else           addr = ((size_t)(col >> 10) << 19) + ((size_t)row << 10) + (size_t)(col & 1023);
        C[addr] = f2bf(v);
      }
    }
  }
}

// ---------- fused flash attention over 3 timeframes ----------
// grid 256: block = (b, qt) XCD-swizzled; 4 waves x 16 q-rows = 64 q-rows/block
__global__ __launch_bounds__(256, 1)
void k_attn(const unsigned short* __restrict__ Qb, const unsigned short* __restrict__ Kb,
            const unsigned short* __restrict__ Vt, const float* __restrict__ tfw,
            float* __restrict__ out){
  __shared__ unsigned short K_lds[64 * 512];   // keys x d, swizzled
  __shared__ unsigned short V_lds[512 * 64];   // d x keys, swizzled
  const int tid = threadIdx.x;
  const int l = tid & 63;
  const int wid = tid >> 6;
  const int lr = l & 15, lg = l >> 4;
  const int bi = blockIdx.x;
  const int b  = (bi & 7) + 8 * (bi >> 7);     // all 16 q-tiles of one b land on same XCD
  const int qt = (bi >> 3) & 15;

  float t0 = tfw[0], t1 = tfw[1], t2 = tfw[2];
  float tm = fmaxf(t0, fmaxf(t1, t2));
  float e0 = __expf(t0 - tm), e1 = __expf(t1 - tm), e2 = __expf(t2 - tm);
  float wsum = e0 + e1 + e2;
  float wts[3] = {e0 / wsum, e1 / wsum, e2 / wsum};

  const float SC = 0.04419417382415922f;       // 1/sqrt(512)
  const f32x4 zero4 = {0.f, 0.f, 0.f, 0.f};

  #pragma unroll 1
  for (int t = 0; t < 3; ++t){
    const size_t bt = (size_t)(b * 3 + t);
    // Q fragments, register-resident: 16 k-steps of K=32
    const int qrow = qt * 64 + wid * 16 + lr;
    const unsigned short* qp = Qb + ((bt << 10) + (size_t)qrow) * 512 + lg * 8;
    bf16x8 qf[16];
    #pragma unroll
    for (int ks = 0; ks < 16; ++ks) qf[ks] = *(const bf16x8*)(qp + ks * 32);

    f32x4 O[32];
    #pragma unroll
    for (int jd = 0; jd < 32; ++jd) O[jd] = zero4;
    float m[4]    = {-1e30f, -1e30f, -1e30f, -1e30f};
    float lsum[4] = {0.f, 0.f, 0.f, 0.f};

    const unsigned short* kb_t = Kb + (bt << 19);
    const unsigned short* vb_t = Vt + (bt << 19);

    #pragma unroll 1
    for (int kt = 0; kt < 16; ++kt){
      const int k0 = kt * 64;
      // ---- stage K tile [64][512] and Vt tile [512][64] (chunk-XOR swizzle) ----
      {
        u16x8 tk[16];
        #pragma unroll
        for (int i = 0; i < 16; ++i){
          int j = i * 256 + tid; int r = j >> 6, c = j & 63;
          tk[i] = *(const u16x8*)(kb_t + (size_t)(k0 + r) * 512 + c * 8);
        }
        #pragma unroll
        for (int i = 0; i < 16; ++i){
          int j = i * 256 + tid; int r = j >> 6, c = j & 63;
          *(u16x8*)(&K_lds[(r << 9) + ((c ^ (r & 7)) << 3)]) = tk[i];
        }
        u16x8 tv[16];
        #pragma unroll
        for (int i = 0; i < 16; ++i){
          int j = i * 256 + tid; int d = j >> 3, c = j & 7;
          tv[i] = *(const u16x8*)(vb_t + ((size_t)d << 10) + k0 + c * 8);
        }
        #pragma unroll
        for (int i = 0; i < 16; ++i){
          int j = i * 256 + tid; int d = j >> 3, c = j & 7;
          *(u16x8*)(&V_lds[(d << 6) + ((c ^ (d & 7)) << 3)]) = tv[i];
        }
      }
      __syncthreads();

      // ---- QK^T: S[16 q][64 keys] per wave ----
      f32x4 s[4] = {zero4, zero4, zero4, zero4};
      #pragma unroll
      for (int ks = 0; ks < 16; ++ks){
        #pragma unroll
        for (int j = 0; j < 4; ++j){
          int key = j * 16 + lr;
          int ch = (ks * 4 + lg) ^ (key & 7);
          bf16x8 kf = *(const bf16x8*)(&K_lds[(key << 9) + (ch << 3)]);
          s[j] = __builtin_amdgcn_mfma_f32_16x16x32_bf16(qf[ks], kf, s[j], 0, 0, 0);
        }
      }

      // ---- online softmax (row stats across 16-lane col groups) ----
      float f[4];
      #pragma unroll
      for (int r = 0; r < 4; ++r){
        float x = fmaxf(fmaxf(s[0][r], s[1][r]), fmaxf(s[2][r], s[3][r]));
        x = fmaxf(x, __shfl_xor(x, 1));
        x = fmaxf(x, __shfl_xor(x, 2));
        x = fmaxf(x, __shfl_xor(x, 4));
        x = fmaxf(x, __shfl_xor(x, 8));
        float mn = fmaxf(m[r], x);
        f[r] = __expf((m[r] - mn) * SC);
        m[r] = mn;
      }
      #pragma unroll
      for (int j = 0; j < 4; ++j)
        #pragma unroll
        for (int r = 0; r < 4; ++r)
          s[j][r] = __expf((s[j][r] - m[r]) * SC);
      #pragma unroll
      for (int r = 0; r < 4; ++r){
        float x = s[0][r] + s[1][r] + s[2][r] + s[3][r];
        x += __shfl_xor(x, 1);
        x += __shfl_xor(x, 2);
        x += __shfl_xor(x, 4);
        x += __shfl_xor(x, 8);
        lsum[r] = lsum[r] * f[r] + x;
      }
      #pragma unroll
      for (int jd = 0; jd < 32; ++jd)
        #pragma unroll
        for (int r = 0; r < 4; ++r) O[jd][r] *= f[r];
      __syncthreads();   // everyone finished reading K_lds

      // ---- P -> LDS (per-wave 2KB overlay in consumed K region), re-read as A-frags ----
      unsigned short* Pw = &K_lds[wid * 1024];
      #pragma unroll
      for (int j = 0; j < 4; ++j){
        int col = j * 16 + lr;
        #pragma unroll
        for (int r = 0; r < 4; ++r)
          Pw[(lg * 4 + r) * 64 + col] = f2bf(s[j][r]);
      }
      bf16x8 pa0 = *(const bf16x8*)(&Pw[lr * 64 + lg * 8]);
      bf16x8 pa1 = *(const bf16x8*)(&Pw[lr * 64 + 32 + lg * 8]);

      // ---- PV: O[16 q][512 d] += P[16][64] * V[64][512] ----
      #pragma unroll
      for (int jd = 0; jd < 32; ++jd){
        int d = jd * 16 + lr;
        int ch0 = lg ^ (d & 7);
        int ch1 = (4 + lg) ^ (d & 7);
        bf16x8 v0 = *(const bf16x8*)(&V_lds[(d << 6) + (ch0 << 3)]);
        O[jd] = __builtin_amdgcn_mfma_f32_16x16x32_bf16(pa0, v0, O[jd], 0, 0, 0);
        bf16x8 v1 = *(const bf16x8*)(&V_lds[(d << 6) + (ch1 << 3)]);
        O[jd] = __builtin_amdgcn_mfma_f32_16x16x32_bf16(pa1, v1, O[jd], 0, 0, 0);
      }
      __syncthreads();
    }

    // ---- accumulate weighted, normalized output (block owns these rows) ----
    float wt = wts[t];
    float inv[4];
    #pragma unroll
    for (int r = 0; r < 4; ++r) inv[r] = wt / lsum[r];
    float* ob = out + ((size_t)b * 1024 + (size_t)(qt * 64 + wid * 16)) * 512;
    #pragma unroll
    for (int jd = 0; jd < 32; ++jd){
      #pragma unroll
      for (int r = 0; r < 4; ++r){
        size_t addr = (size_t)(lg * 4 + r) * 512 + (size_t)(jd * 16 + lr);
        float v = O[jd][r] * inv[r];
        if (t == 0) ob[addr] = v;
        else        ob[addr] += v;
      }
    }
  }
}

extern "C" void kernel_launch(void* const* d_in, const int* in_sizes, int n_in,
                              void* d_out, int out_size, void* d_ws, size_t ws_size,
                              hipStream_t stream){
  (void)in_sizes; (void)n_in; (void)out_size; (void)ws_size;
  const float* f4h = (const float*)d_in[0];
  const float* f1d = (const float*)d_in[1];
  const float* f1w = (const float*)d_in[2];
  const float* Wq  = (const float*)d_in[3];
  const float* bq  = (const float*)d_in[4];
  const float* Wk  = (const float*)d_in[5];
  const float* bk  = (const float*)d_in[6];
  const float* Wv  = (const float*)d_in[7];
  const float* bv  = (const float*)d_in[8];
  const float* tfw = (const float*)d_in[9];

  const size_t NBTSD = (size_t)48 * 1024 * 512;   // 25165824 elems
  unsigned short* Xb = (unsigned short*)d_ws;
  unsigned short* Qb = Xb + NBTSD;
  unsigned short* Kb = Qb + NBTSD;
  unsigned short* Vt = Kb + NBTSD;
  unsigned short* Wb = Vt + NBTSD;                // 3*512*512 elems

  k_conv_feat<<<12288, 256, 0, stream>>>(f4h, f1d, f1w, Xb);
  k_conv_w<<<384, 256, 0, stream>>>(Wq, Wk, Wv, Wb);
  k_gemm_bt<0><<<1536, 256, 0, stream>>>(Xb, Wb,          bq, Qb, 512);
  k_gemm_bt<0><<<1536, 256, 0, stream>>>(Xb, Wb + 262144, bk, Kb, 512);
  k_gemm_bt<1><<<1536, 256, 0, stream>>>(Wb + 524288, Xb, bv, Vt, 49152);
  k_attn<<<256, 256, 0, stream>>>(Qb, Kb, Vt, tfw, (float*)d_out);
}

// Round 2
// 349.871 us; speedup vs baseline: 2.5907x; 2.5907x over previous
//
#include <hip/hip_runtime.h>

typedef __bf16 bf16x8 __attribute__((ext_vector_type(8)));
typedef unsigned short u16x8 __attribute__((ext_vector_type(8)));
typedef float f32x4 __attribute__((ext_vector_type(4)));

// sizes: B=16, S=1024, D=512, T=3, BT=48
// Qb/Kb layout: [bt][s][d] bf16 ; Vt layout: [bt][d][s] bf16
// Sbuf: [bt][q][k] fp16 scores, overwritten in-place by bf16 P = w[t]*exp/l

__device__ __forceinline__ unsigned short f2bf(float x){
  unsigned u = __float_as_uint(x);
  u += 0x7fffu + ((u >> 16) & 1u);
  return (unsigned short)(u >> 16);
}

// ---------- convert features fp32 -> bf16, stacked [48][1024][512] ----------
__global__ void k_conv_feat(const float* __restrict__ f0, const float* __restrict__ f1,
                            const float* __restrict__ f2, unsigned short* __restrict__ Xb){
  size_t i = (size_t)blockIdx.x * blockDim.x + threadIdx.x;
  size_t e = i * 8;
  size_t bt = e >> 19;
  size_t rest = e & ((1u << 19) - 1);
  int b = (int)(bt / 3), t = (int)(bt % 3);
  const float* src = (t == 0 ? f0 : (t == 1 ? f1 : f2)) + ((size_t)b << 19) + rest;
  f32x4 v0 = *(const f32x4*)(src);
  f32x4 v1 = *(const f32x4*)(src + 4);
  u16x8 o;
  o[0] = f2bf(v0[0]); o[1] = f2bf(v0[1]); o[2] = f2bf(v0[2]); o[3] = f2bf(v0[3]);
  o[4] = f2bf(v1[0]); o[5] = f2bf(v1[1]); o[6] = f2bf(v1[2]); o[7] = f2bf(v1[3]);
  *(u16x8*)(Xb + e) = o;
}

// ---------- convert weights fp32 -> bf16, Wb = [Wq|Wk|Wv] each [512][512] ----------
__global__ void k_conv_w(const float* __restrict__ wq, const float* __restrict__ wk,
                         const float* __restrict__ wv, unsigned short* __restrict__ Wb){
  size_t i = (size_t)blockIdx.x * blockDim.x + threadIdx.x;
  size_t e = i * 8;
  int sel = (int)(e >> 18);
  size_t rest = e & ((1u << 18) - 1);
  const float* src = (sel == 0 ? wq : (sel == 1 ? wk : wv)) + rest;
  f32x4 v0 = *(const f32x4*)(src);
  f32x4 v1 = *(const f32x4*)(src + 4);
  u16x8 o;
  o[0] = f2bf(v0[0]); o[1] = f2bf(v0[1]); o[2] = f2bf(v0[2]); o[3] = f2bf(v0[3]);
  o[4] = f2bf(v1[0]); o[5] = f2bf(v1[1]); o[6] = f2bf(v1[2]); o[7] = f2bf(v1[3]);
  *(u16x8*)(Wb + e) = o;
}

// ---------- projection GEMM: C = (A * B^T + bias) * scale, bf16 out. K=512. ----------
// MODE 0: C[m][n] at m*N+n, bias[n]       (Q, K projections)
// MODE 1: C[m][n] at (n>>10)<<19 | m<<10 | (n&1023), bias[m]   (Vt)
template<int MODE>
__global__ __launch_bounds__(256, 2)
void k_gemm_proj(const unsigned short* __restrict__ A, const unsigned short* __restrict__ Bm,
                 const float* __restrict__ bias, unsigned short* __restrict__ C, int N, float scale){
  __shared__ unsigned short Al[2][128 * 64];
  __shared__ unsigned short Bl[2][128 * 64];
  const int tid = threadIdx.x;
  const int l  = tid & 63;
  const int wid = tid >> 6;
  const int lr = l & 15;
  const int lg = l >> 4;
  const int nbc = N >> 7;
  const int rb = blockIdx.x / nbc;
  const int cb = blockIdx.x % nbc;
  const unsigned short* Ab = A + (size_t)rb * 128 * 512;
  const unsigned short* Bb = Bm + (size_t)cb * 128 * 512;

  const f32x4 zero4 = {0.f, 0.f, 0.f, 0.f};
  f32x4 acc[4][4];
  #pragma unroll
  for (int i = 0; i < 4; ++i)
    #pragma unroll
    for (int j = 0; j < 4; ++j) acc[i][j] = zero4;

  {
    u16x8 va[4], vb[4];
    #pragma unroll
    for (int i = 0; i < 4; ++i){
      int j = i * 256 + tid; int r = j >> 3, c = j & 7;
      va[i] = *(const u16x8*)(Ab + (size_t)r * 512 + c * 8);
      vb[i] = *(const u16x8*)(Bb + (size_t)r * 512 + c * 8);
    }
    #pragma unroll
    for (int i = 0; i < 4; ++i){
      int j = i * 256 + tid; int r = j >> 3, c = j & 7;
      int cc = c ^ (r & 7);
      *(u16x8*)(&Al[0][(r << 6) + (cc << 3)]) = va[i];
      *(u16x8*)(&Bl[0][(r << 6) + (cc << 3)]) = vb[i];
    }
  }
  __syncthreads();

  const int wr = wid >> 1, wc = wid & 1;

  for (int kb = 0; kb < 8; ++kb){
    const int cur = kb & 1;
    u16x8 va[4], vb[4];
    if (kb < 7){
      #pragma unroll
      for (int i = 0; i < 4; ++i){
        int j = i * 256 + tid; int r = j >> 3, c = j & 7;
        va[i] = *(const u16x8*)(Ab + (size_t)r * 512 + (kb + 1) * 64 + c * 8);
        vb[i] = *(const u16x8*)(Bb + (size_t)r * 512 + (kb + 1) * 64 + c * 8);
      }
    }
    #pragma unroll
    for (int ks = 0; ks < 2; ++ks){
      bf16x8 af[4], bf[4];
      #pragma unroll
      for (int i = 0; i < 4; ++i){
        int row = wr * 64 + i * 16 + lr;
        int ch = (ks * 4 + lg) ^ (row & 7);
        af[i] = *(const bf16x8*)(&Al[cur][(row << 6) + (ch << 3)]);
      }
      #pragma unroll
      for (int j = 0; j < 4; ++j){
        int row = wc * 64 + j * 16 + lr;
        int ch = (ks * 4 + lg) ^ (row & 7);
        bf[j] = *(const bf16x8*)(&Bl[cur][(row << 6) + (ch << 3)]);
      }
      #pragma unroll
      for (int i = 0; i < 4; ++i)
        #pragma unroll
        for (int j = 0; j < 4; ++j)
          acc[i][j] = __builtin_amdgcn_mfma_f32_16x16x32_bf16(af[i], bf[j], acc[i][j], 0, 0, 0);
    }
    __syncthreads();
    if (kb < 7){
      #pragma unroll
      for (int i = 0; i < 4; ++i){
        int j = i * 256 + tid; int r = j >> 3, c = j & 7;
        int cc = c ^ (r & 7);
        *(u16x8*)(&Al[cur ^ 1][(r << 6) + (cc << 3)]) = va[i];
        *(u16x8*)(&Bl[cur ^ 1][(r << 6) + (cc << 3)]) = vb[i];
      }
      __syncthreads();
    }
  }

  #pragma unroll
  for (int j = 0; j < 4; ++j){
    int col = cb * 128 + wc * 64 + j * 16 + lr;
    float bc = (MODE == 0) ? bias[col] : 0.f;
    #pragma unroll
    for (int i = 0; i < 4; ++i){
      int row0 = rb * 128 + wr * 64 + i * 16 + lg * 4;
      #pragma unroll
      for (int r = 0; r < 4; ++r){
        int row = row0 + r;
        float v = (acc[i][j][r] + ((MODE == 0) ? bc : bias[row])) * scale;
        size_t addr;
        if (MODE == 0) addr = (size_t)row * N + col;
        else           addr = ((size_t)(col >> 10) << 19) + ((size_t)row << 10) + (size_t)(col & 1023);
        C[addr] = f2bf(v);
      }
    }
  }
}

// ---------- S = Q' * K^T, fp16 out. Batched over bt. Q' already has 1/sqrt(D). ----------
__global__ __launch_bounds__(256, 2)
void k_gemm_qk(const unsigned short* __restrict__ Qb, const unsigned short* __restrict__ Kb,
               unsigned short* __restrict__ S, int bt0){
  __shared__ unsigned short Al[2][128 * 64];
  __shared__ unsigned short Bl[2][128 * 64];
  const int tid = threadIdx.x;
  const int l  = tid & 63;
  const int wid = tid >> 6;
  const int lr = l & 15;
  const int lg = l >> 4;
  const int bi = blockIdx.x;
  const int bt = bt0 + (bi >> 6);
  const int tile = bi & 63;
  const int rb = tile >> 3, cb = tile & 7;
  const unsigned short* Ab = Qb + ((size_t)bt << 19) + (size_t)rb * 128 * 512;
  const unsigned short* Bb = Kb + ((size_t)bt << 19) + (size_t)cb * 128 * 512;
  unsigned short* Cb = S + ((size_t)(bt - bt0) << 20);

  const f32x4 zero4 = {0.f, 0.f, 0.f, 0.f};
  f32x4 acc[4][4];
  #pragma unroll
  for (int i = 0; i < 4; ++i)
    #pragma unroll
    for (int j = 0; j < 4; ++j) acc[i][j] = zero4;

  {
    u16x8 va[4], vb[4];
    #pragma unroll
    for (int i = 0; i < 4; ++i){
      int j = i * 256 + tid; int r = j >> 3, c = j & 7;
      va[i] = *(const u16x8*)(Ab + (size_t)r * 512 + c * 8);
      vb[i] = *(const u16x8*)(Bb + (size_t)r * 512 + c * 8);
    }
    #pragma unroll
    for (int i = 0; i < 4; ++i){
      int j = i * 256 + tid; int r = j >> 3, c = j & 7;
      int cc = c ^ (r & 7);
      *(u16x8*)(&Al[0][(r << 6) + (cc << 3)]) = va[i];
      *(u16x8*)(&Bl[0][(r << 6) + (cc << 3)]) = vb[i];
    }
  }
  __syncthreads();

  const int wr = wid >> 1, wc = wid & 1;

  for (int kb = 0; kb < 8; ++kb){
    const int cur = kb & 1;
    u16x8 va[4], vb[4];
    if (kb < 7){
      #pragma unroll
      for (int i = 0; i < 4; ++i){
        int j = i * 256 + tid; int r = j >> 3, c = j & 7;
        va[i] = *(const u16x8*)(Ab + (size_t)r * 512 + (kb + 1) * 64 + c * 8);
        vb[i] = *(const u16x8*)(Bb + (size_t)r * 512 + (kb + 1) * 64 + c * 8);
      }
    }
    #pragma unroll
    for (int ks = 0; ks < 2; ++ks){
      bf16x8 af[4], bf[4];
      #pragma unroll
      for (int i = 0; i < 4; ++i){
        int row = wr * 64 + i * 16 + lr;
        int ch = (ks * 4 + lg) ^ (row & 7);
        af[i] = *(const bf16x8*)(&Al[cur][(row << 6) + (ch << 3)]);
      }
      #pragma unroll
      for (int j = 0; j < 4; ++j){
        int row = wc * 64 + j * 16 + lr;
        int ch = (ks * 4 + lg) ^ (row & 7);
        bf[j] = *(const bf16x8*)(&Bl[cur][(row << 6) + (ch << 3)]);
      }
      #pragma unroll
      for (int i = 0; i < 4; ++i)
        #pragma unroll
        for (int j = 0; j < 4; ++j)
          acc[i][j] = __builtin_amdgcn_mfma_f32_16x16x32_bf16(af[i], bf[j], acc[i][j], 0, 0, 0);
    }
    __syncthreads();
    if (kb < 7){
      #pragma unroll
      for (int i = 0; i < 4; ++i){
        int j = i * 256 + tid; int r = j >> 3, c = j & 7;
        int cc = c ^ (r & 7);
        *(u16x8*)(&Al[cur ^ 1][(r << 6) + (cc << 3)]) = va[i];
        *(u16x8*)(&Bl[cur ^ 1][(r << 6) + (cc << 3)]) = vb[i];
      }
      __syncthreads();
    }
  }

  // epilogue: fp16 store, addr = row*1024 + col
  #pragma unroll
  for (int j = 0; j < 4; ++j){
    int col = cb * 128 + wc * 64 + j * 16 + lr;
    #pragma unroll
    for (int i = 0; i < 4; ++i){
      int row0 = rb * 128 + wr * 64 + i * 16 + lg * 4;
      #pragma unroll
      for (int r = 0; r < 4; ++r){
        int row = row0 + r;
        _Float16 h = (_Float16)acc[i][j][r];
        Cb[((size_t)row << 10) + col] = __builtin_bit_cast(unsigned short, h);
      }
    }
  }
}

// ---------- softmax rows, in place: fp16 S -> bf16 P = w[t]*exp(s-m)/l ----------
__global__ __launch_bounds__(256)
void k_softmax(unsigned short* __restrict__ S, const float* __restrict__ tfw, int bt0){
  const int wid = threadIdx.x >> 6, l = threadIdx.x & 63;
  const size_t row = (size_t)blockIdx.x * 4 + wid;
  const int bt = bt0 + (int)(row >> 10);
  const int t = bt % 3;
  float t0 = tfw[0], t1 = tfw[1], t2 = tfw[2];
  float tm = fmaxf(t0, fmaxf(t1, t2));
  float e0 = __expf(t0 - tm), e1 = __expf(t1 - tm), e2 = __expf(t2 - tm);
  float w = (t == 0 ? e0 : (t == 1 ? e1 : e2)) / (e0 + e1 + e2);

  unsigned short* rp = S + (row << 10) + l * 16;
  u16x8 a = *(const u16x8*)rp;
  u16x8 b = *(const u16x8*)(rp + 8);
  float x[16];
  #pragma unroll
  for (int j = 0; j < 8; ++j){
    x[j]     = (float)__builtin_bit_cast(_Float16, (unsigned short)a[j]);
    x[8 + j] = (float)__builtin_bit_cast(_Float16, (unsigned short)b[j]);
  }
  float m = x[0];
  #pragma unroll
  for (int j = 1; j < 16; ++j) m = fmaxf(m, x[j]);
  m = fmaxf(m, __shfl_xor(m, 1));
  m = fmaxf(m, __shfl_xor(m, 2));
  m = fmaxf(m, __shfl_xor(m, 4));
  m = fmaxf(m, __shfl_xor(m, 8));
  m = fmaxf(m, __shfl_xor(m, 16));
  m = fmaxf(m, __shfl_xor(m, 32));
  float s = 0.f;
  #pragma unroll
  for (int j = 0; j < 16; ++j){ x[j] = __expf(x[j] - m); s += x[j]; }
  s += __shfl_xor(s, 1);
  s += __shfl_xor(s, 2);
  s += __shfl_xor(s, 4);
  s += __shfl_xor(s, 8);
  s += __shfl_xor(s, 16);
  s += __shfl_xor(s, 32);
  float sc = w / s;
  u16x8 oa, ob;
  #pragma unroll
  for (int j = 0; j < 8; ++j){
    oa[j] = f2bf(x[j] * sc);
    ob[j] = f2bf(x[8 + j] * sc);
  }
  *(u16x8*)rp = oa;
  *(u16x8*)(rp + 8) = ob;
}

// ---------- out[b] = sum_t P[b,t] * V[b,t]  (f32 out, K-dim = 3*1024) ----------
__global__ __launch_bounds__(256, 2)
void k_gemm_pv(const unsigned short* __restrict__ P, const unsigned short* __restrict__ Vt,
               float* __restrict__ out, int b0){
  __shared__ unsigned short Al[2][128 * 64];
  __shared__ unsigned short Bl[2][128 * 64];
  const int tid = threadIdx.x;
  const int l  = tid & 63;
  const int wid = tid >> 6;
  const int lr = l & 15;
  const int lg = l >> 4;
  const int bi = blockIdx.x;
  const int b = b0 + (bi >> 5);
  const int tile = bi & 31;
  const int rb = tile >> 2, cb = tile & 3;   // rb: q-block (8), cb: d-block (4)

  const f32x4 zero4 = {0.f, 0.f, 0.f, 0.f};
  f32x4 acc[4][4];
  #pragma unroll
  for (int i = 0; i < 4; ++i)
    #pragma unroll
    for (int j = 0; j < 4; ++j) acc[i][j] = zero4;

  // stage k-tile kb into buffer `dst`
  // kb in [0,48): t = kb>>4, kk = kb&15
  {
    const unsigned short* Ab = P  + ((size_t)((b - b0) * 3) << 20) + (size_t)rb * 128 * 1024;
    const unsigned short* Bb = Vt + ((size_t)(b * 3) << 19) + (size_t)cb * 128 * 1024;
    u16x8 va[4], vb[4];
    #pragma unroll
    for (int i = 0; i < 4; ++i){
      int j = i * 256 + tid; int r = j >> 3, c = j & 7;
      va[i] = *(const u16x8*)(Ab + (size_t)r * 1024 + c * 8);
      vb[i] = *(const u16x8*)(Bb + (size_t)r * 1024 + c * 8);
    }
    #pragma unroll
    for (int i = 0; i < 4; ++i){
      int j = i * 256 + tid; int r = j >> 3, c = j & 7;
      int cc = c ^ (r & 7);
      *(u16x8*)(&Al[0][(r << 6) + (cc << 3)]) = va[i];
      *(u16x8*)(&Bl[0][(r << 6) + (cc << 3)]) = vb[i];
    }
  }
  __syncthreads();

  const int wr = wid >> 1, wc = wid & 1;

  #pragma unroll 2
  for (int kb = 0; kb < 48; ++kb){
    const int cur = kb & 1;
    u16x8 va[4], vb[4];
    if (kb < 47){
      int kn = kb + 1;
      int t = kn >> 4, kk = kn & 15;
      const unsigned short* Ab = P  + ((size_t)((b - b0) * 3 + t) << 20) + (size_t)rb * 128 * 1024 + kk * 64;
      const unsigned short* Bb = Vt + ((size_t)(b * 3 + t) << 19) + (size_t)cb * 128 * 1024 + kk * 64;
      #pragma unroll
      for (int i = 0; i < 4; ++i){
        int j = i * 256 + tid; int r = j >> 3, c = j & 7;
        va[i] = *(const u16x8*)(Ab + (size_t)r * 1024 + c * 8);
        vb[i] = *(const u16x8*)(Bb + (size_t)r * 1024 + c * 8);
      }
    }
    #pragma unroll
    for (int ks = 0; ks < 2; ++ks){
      bf16x8 af[4], bf[4];
      #pragma unroll
      for (int i = 0; i < 4; ++i){
        int row = wr * 64 + i * 16 + lr;
        int ch = (ks * 4 + lg) ^ (row & 7);
        af[i] = *(const bf16x8*)(&Al[cur][(row << 6) + (ch << 3)]);
      }
      #pragma unroll
      for (int j = 0; j < 4; ++j){
        int row = wc * 64 + j * 16 + lr;
        int ch = (ks * 4 + lg) ^ (row & 7);
        bf[j] = *(const bf16x8*)(&Bl[cur][(row << 6) + (ch << 3)]);
      }
      #pragma unroll
      for (int i = 0; i < 4; ++i)
        #pragma unroll
        for (int j = 0; j < 4; ++j)
          acc[i][j] = __builtin_amdgcn_mfma_f32_16x16x32_bf16(af[i], bf[j], acc[i][j], 0, 0, 0);
    }
    __syncthreads();
    if (kb < 47){
      #pragma unroll
      for (int i = 0; i < 4; ++i){
        int j = i * 256 + tid; int r = j >> 3, c = j & 7;
        int cc = c ^ (r & 7);
        *(u16x8*)(&Al[cur ^ 1][(r << 6) + (cc << 3)]) = va[i];
        *(u16x8*)(&Bl[cur ^ 1][(r << 6) + (cc << 3)]) = vb[i];
      }
      __syncthreads();
    }
  }

  // epilogue: f32 out[b][q][d]
  float* ob = out + ((size_t)b << 19);
  #pragma unroll
  for (int j = 0; j < 4; ++j){
    int col = cb * 128 + wc * 64 + j * 16 + lr;
    #pragma unroll
    for (int i = 0; i < 4; ++i){
      int row0 = rb * 128 + wr * 64 + i * 16 + lg * 4;
      #pragma unroll
      for (int r = 0; r < 4; ++r){
        int row = row0 + r;
        ob[((size_t)row << 9) + col] = acc[i][j][r];
      }
    }
  }
}

extern "C" void kernel_launch(void* const* d_in, const int* in_sizes, int n_in,
                              void* d_out, int out_size, void* d_ws, size_t ws_size,
                              hipStream_t stream){
  (void)in_sizes; (void)n_in; (void)out_size;
  const float* f4h = (const float*)d_in[0];
  const float* f1d = (const float*)d_in[1];
  const float* f1w = (const float*)d_in[2];
  const float* Wq  = (const float*)d_in[3];
  const float* bq  = (const float*)d_in[4];
  const float* Wk  = (const float*)d_in[5];
  const float* bk  = (const float*)d_in[6];
  const float* Wv  = (const float*)d_in[7];
  const float* bv  = (const float*)d_in[8];
  const float* tfw = (const float*)d_in[9];
  float* out = (float*)d_out;

  const size_t N48 = (size_t)48 * 1024 * 512;     // 25165824 elems
  unsigned short* ws16 = (unsigned short*)d_ws;
  unsigned short* Qb = ws16;                      // live to end
  unsigned short* Kb = Qb + N48;                  // live to end
  unsigned short* Vt = Kb + N48;                  // live to end
  unsigned short* Xb = Vt + N48;                  // dead after proj GEMMs
  unsigned short* Wb = Xb + N48;                  // dead after proj GEMMs
  unsigned short* Sb = Xb;                        // S/P overlays Xb (+Wb +tail if full)

  const float SC = 0.04419417382415922f;          // 1/sqrt(512)

  k_conv_feat<<<12288, 256, 0, stream>>>(f4h, f1d, f1w, Xb);
  k_conv_w<<<384, 256, 0, stream>>>(Wq, Wk, Wv, Wb);
  k_gemm_proj<0><<<1536, 256, 0, stream>>>(Xb, Wb,          bq, Qb, 512, SC);
  k_gemm_proj<0><<<1536, 256, 0, stream>>>(Xb, Wb + 262144, bk, Kb, 512, 1.0f);
  k_gemm_proj<1><<<1536, 256, 0, stream>>>(Wb + 524288, Xb, bv, Vt, 49152, 1.0f);

  // S full needs 48*1024*1024*2 B starting at Xb: total ws = 3*N48*2 + 100663296
  const size_t need_full = 3 * N48 * 2 + (size_t)48 * 1024 * 1024 * 2;  // 251658240
  if (ws_size >= need_full){
    k_gemm_qk<<<3072, 256, 0, stream>>>(Qb, Kb, Sb, 0);
    k_softmax<<<12288, 256, 0, stream>>>(Sb, tfw, 0);
    k_gemm_pv<<<512, 256, 0, stream>>>(Sb, Vt, out, 0);
  } else {
    // two halves of 8 batches (24 bt): S-half = 48 MB = exactly the Xb region
    for (int h = 0; h < 2; ++h){
      int bt0 = h * 24;
      k_gemm_qk<<<1536, 256, 0, stream>>>(Qb, Kb, Sb, bt0);
      k_softmax<<<6144, 256, 0, stream>>>(Sb, tfw, bt0);
      k_gemm_pv<<<256, 256, 0, stream>>>(Sb, Vt, out, h * 8);
    }
  }
}

// Round 3
// 273.642 us; speedup vs baseline: 3.3124x; 1.2786x over previous
//
#include <hip/hip_runtime.h>
#include <cstdint>

typedef __bf16 bf16x8 __attribute__((ext_vector_type(8)));
typedef unsigned short u16x8 __attribute__((ext_vector_type(8)));
typedef float f32x4 __attribute__((ext_vector_type(4)));

// B=16, S=1024, D=512, T=3, BT=48
// Xb [bt][s][d] bf16 ; Gb [bt][s][d'] bf16 (= X * (SC*Wq^T*Wk)) ; Vt [bt][e][s] bf16
// S/P buffer: [bt_local][q][k] fp16 scores -> bf16 P in place

__device__ __forceinline__ unsigned short f2bf(float x){
  unsigned u = __float_as_uint(x);
  u += 0x7fffu + ((u >> 16) & 1u);
  return (unsigned short)(u >> 16);
}

__device__ __forceinline__ void gload16(const void* src, void* dst){
  auto g = reinterpret_cast<const uint32_t __attribute__((address_space(1)))*>(
             reinterpret_cast<uintptr_t>(src));
  auto l = reinterpret_cast<uint32_t __attribute__((address_space(3)))*>(
             reinterpret_cast<uintptr_t>(dst));
  __builtin_amdgcn_global_load_lds(g, l, 16, 0, 0);
}

// stage one 128x64 bf16 tile: linear LDS chunks, inverse-swizzled global source.
// LDS chunk (r,cc) receives global chunk c = cc ^ (r&7); readers use the same XOR.
__device__ __forceinline__ void stage_tile(const unsigned short* __restrict__ g, size_t ld,
                                           unsigned short* l, int tid){
  #pragma unroll
  for (int i = 0; i < 4; ++i){
    int j = i * 256 + tid;
    int r = j >> 3, cc = j & 7;
    int c = cc ^ (r & 7);
    gload16(g + (size_t)r * ld + c * 8, l + (size_t)(i * 256 + (tid & 192)) * 8);
  }
}

__device__ __forceinline__ bf16x8 frag_at(const unsigned short* l, int row, int kch){
  int ch = kch ^ (row & 7);
  return *(const bf16x8*)(l + (row << 6) + (ch << 3));
}

// ---------- w1 = SC * Wk^T * bq ----------
__global__ void k_w1(const float* __restrict__ Wk, const float* __restrict__ bq,
                     float* __restrict__ w1){
  __shared__ float red[4][64];
  int d = blockIdx.x * 64 + (threadIdx.x & 63);
  int eq = threadIdx.x >> 6;
  float s = 0.f;
  #pragma unroll 8
  for (int e = eq * 128; e < eq * 128 + 128; ++e) s += Wk[(size_t)e * 512 + d] * bq[e];
  red[eq][threadIdx.x & 63] = s;
  __syncthreads();
  if (eq == 0)
    w1[d] = (red[0][threadIdx.x] + red[1][threadIdx.x] + red[2][threadIdx.x] +
             red[3][threadIdx.x]) * 0.04419417382415922f;
}

// ---------- transpose+convert Wq,Wk -> WqT,WkT ([d][e] bf16) ----------
__global__ void k_conv_wt(const float* __restrict__ Wq, const float* __restrict__ Wk,
                          unsigned short* __restrict__ WqT, unsigned short* __restrict__ WkT){
  __shared__ float tl[64][65];
  int bi = blockIdx.x;
  const float* src = (bi & 64) ? Wk : Wq;
  unsigned short* dst = (bi & 64) ? WkT : WqT;
  int te = (bi >> 3) & 7, td = bi & 7;
  int tid = threadIdx.x;
  #pragma unroll
  for (int i = 0; i < 4; ++i){
    int q = i * 256 + tid;
    int r = q >> 4, c4 = q & 15;
    f32x4 v = *(const f32x4*)(src + (size_t)(te * 64 + r) * 512 + td * 64 + c4 * 4);
    tl[r][c4 * 4 + 0] = v[0]; tl[r][c4 * 4 + 1] = v[1];
    tl[r][c4 * 4 + 2] = v[2]; tl[r][c4 * 4 + 3] = v[3];
  }
  __syncthreads();
  #pragma unroll
  for (int i = 0; i < 2; ++i){
    int q = i * 256 + tid;
    int r = q >> 3, c8 = q & 7;
    u16x8 o;
    #pragma unroll
    for (int j = 0; j < 8; ++j) o[j] = f2bf(tl[c8 * 8 + j][r]);
    *(u16x8*)(dst + (size_t)(td * 64 + r) * 512 + te * 64 + c8 * 8) = o;
  }
}

// ---------- convert Wv fp32 -> bf16 ----------
__global__ void k_conv_wv(const float* __restrict__ Wv, unsigned short* __restrict__ out){
  size_t e = ((size_t)blockIdx.x * 256 + threadIdx.x) * 8;
  f32x4 v0 = *(const f32x4*)(Wv + e), v1 = *(const f32x4*)(Wv + e + 4);
  u16x8 o;
  o[0] = f2bf(v0[0]); o[1] = f2bf(v0[1]); o[2] = f2bf(v0[2]); o[3] = f2bf(v0[3]);
  o[4] = f2bf(v1[0]); o[5] = f2bf(v1[1]); o[6] = f2bf(v1[2]); o[7] = f2bf(v1[3]);
  *(u16x8*)(out + e) = o;
}

// ---------- features fp32 -> bf16 stacked + column bias v = X*w1 ----------
__global__ void k_conv_feat(const float* __restrict__ f0, const float* __restrict__ f1,
                            const float* __restrict__ f2, const float* __restrict__ w1,
                            unsigned short* __restrict__ Xb, float* __restrict__ vcol){
  size_t i = (size_t)blockIdx.x * blockDim.x + threadIdx.x;
  size_t e = i * 8;
  size_t bt = e >> 19;
  size_t rest = e & ((1u << 19) - 1);
  int b = (int)(bt / 3), t = (int)(bt % 3);
  const float* src = (t == 0 ? f0 : (t == 1 ? f1 : f2)) + ((size_t)b << 19) + rest;
  f32x4 v0 = *(const f32x4*)(src);
  f32x4 v1 = *(const f32x4*)(src + 4);
  u16x8 o;
  o[0] = f2bf(v0[0]); o[1] = f2bf(v0[1]); o[2] = f2bf(v0[2]); o[3] = f2bf(v0[3]);
  o[4] = f2bf(v1[0]); o[5] = f2bf(v1[1]); o[6] = f2bf(v1[2]); o[7] = f2bf(v1[3]);
  *(u16x8*)(Xb + e) = o;
  // row-dot with w1 (one wave == one row of 512)
  int l = threadIdx.x & 63;
  f32x4 wa = *(const f32x4*)(w1 + l * 8);
  f32x4 wb = *(const f32x4*)(w1 + l * 8 + 4);
  float p = v0[0]*wa[0] + v0[1]*wa[1] + v0[2]*wa[2] + v0[3]*wa[3]
          + v1[0]*wb[0] + v1[1]*wb[1] + v1[2]*wb[2] + v1[3]*wb[3];
  p += __shfl_xor(p, 1);  p += __shfl_xor(p, 2);  p += __shfl_xor(p, 4);
  p += __shfl_xor(p, 8);  p += __shfl_xor(p, 16); p += __shfl_xor(p, 32);
  if (l == 0) vcol[i >> 6] = p;
}

// ---------- C = (A * B^T + bias) * scale, bf16 out. K=512. ----------
// MODE 0: C[m][n] at m*N+n, bias[n] (nullable)
// MODE 1: C[m][n] at (n>>10)<<19 | m<<10 | (n&1023), bias[m]   (Vt)
template<int MODE>
__global__ __launch_bounds__(256, 2)
void k_gemm_proj(const unsigned short* __restrict__ A, const unsigned short* __restrict__ Bm,
                 const float* __restrict__ bias, unsigned short* __restrict__ C, int N, float scale){
  __shared__ __align__(16) unsigned short Al[2][8192];
  __shared__ __align__(16) unsigned short Bl[2][8192];
  const int tid = threadIdx.x;
  const int l  = tid & 63;
  const int wid = tid >> 6;
  const int lr = l & 15;
  const int lg = l >> 4;
  const int cpx = gridDim.x >> 3;
  const int wg = (blockIdx.x & 7) * cpx + (blockIdx.x >> 3);
  const int nbc = N >> 7;
  int rb, cb;
  if (MODE == 1){ cb = wg >> 2; rb = wg & 3; }
  else          { rb = wg / nbc; cb = wg % nbc; }
  const unsigned short* Ab = A + (size_t)rb * 128 * 512;
  const unsigned short* Bb = Bm + (size_t)cb * 128 * 512;

  const f32x4 zero4 = {0.f, 0.f, 0.f, 0.f};
  f32x4 acc[4][4];
  #pragma unroll
  for (int i = 0; i < 4; ++i)
    #pragma unroll
    for (int j = 0; j < 4; ++j) acc[i][j] = zero4;

  stage_tile(Ab, 512, &Al[0][0], tid);
  stage_tile(Bb, 512, &Bl[0][0], tid);
  __syncthreads();

  const int wr = wid >> 1, wc = wid & 1;

  for (int kb = 0; kb < 8; ++kb){
    const int cur = kb & 1;
    if (kb < 7){
      stage_tile(Ab + (kb + 1) * 64, 512, &Al[cur ^ 1][0], tid);
      stage_tile(Bb + (kb + 1) * 64, 512, &Bl[cur ^ 1][0], tid);
    }
    #pragma unroll
    for (int ks = 0; ks < 2; ++ks){
      bf16x8 af[4], bf[4];
      #pragma unroll
      for (int i = 0; i < 4; ++i) af[i] = frag_at(&Al[cur][0], wr * 64 + i * 16 + lr, ks * 4 + lg);
      #pragma unroll
      for (int j = 0; j < 4; ++j) bf[j] = frag_at(&Bl[cur][0], wc * 64 + j * 16 + lr, ks * 4 + lg);
      #pragma unroll
      for (int i = 0; i < 4; ++i)
        #pragma unroll
        for (int j = 0; j < 4; ++j)
          acc[i][j] = __builtin_amdgcn_mfma_f32_16x16x32_bf16(af[i], bf[j], acc[i][j], 0, 0, 0);
    }
    __syncthreads();
  }

  #pragma unroll
  for (int j = 0; j < 4; ++j){
    int col = cb * 128 + wc * 64 + j * 16 + lr;
    float bc = (MODE == 0 && bias) ? bias[col] : 0.f;
    #pragma unroll
    for (int i = 0; i < 4; ++i){
      int row0 = rb * 128 + wr * 64 + i * 16 + lg * 4;
      #pragma unroll
      for (int r = 0; r < 4; ++r){
        int row = row0 + r;
        float v = (acc[i][j][r] + ((MODE == 0) ? bc : bias[row])) * scale;
        size_t addr;
        if (MODE == 0) addr = (size_t)row * N + col;
        else           addr = ((size_t)(col >> 10) << 19) + ((size_t)row << 10) + (size_t)(col & 1023);
        C[addr] = f2bf(v);
      }
    }
  }
}

// ---------- S = G * X^T, fp16 out. grid = nbt*64, XCD-chunked. ----------
__global__ __launch_bounds__(256, 2)
void k_gemm_qk(const unsigned short* __restrict__ Gb, const unsigned short* __restrict__ Xb,
               unsigned short* __restrict__ S, int bt0){
  __shared__ __align__(16) unsigned short Al[2][8192];
  __shared__ __align__(16) unsigned short Bl[2][8192];
  const int tid = threadIdx.x;
  const int l  = tid & 63;
  const int wid = tid >> 6;
  const int lr = l & 15;
  const int lg = l >> 4;
  const int cpx = gridDim.x >> 3;
  const int wg = (blockIdx.x & 7) * cpx + (blockIdx.x >> 3);
  const int btl = wg >> 6;             // local bt
  const int bt = bt0 + btl;
  const int tile = wg & 63;
  const int rb = tile >> 3, cb = tile & 7;
  const unsigned short* Ab = Gb + ((size_t)bt << 19) + (size_t)rb * 128 * 512;
  const unsigned short* Bb = Xb + ((size_t)bt << 19) + (size_t)cb * 128 * 512;
  unsigned short* Cb = S + ((size_t)btl << 20);

  const f32x4 zero4 = {0.f, 0.f, 0.f, 0.f};
  f32x4 acc[4][4];
  #pragma unroll
  for (int i = 0; i < 4; ++i)
    #pragma unroll
    for (int j = 0; j < 4; ++j) acc[i][j] = zero4;

  stage_tile(Ab, 512, &Al[0][0], tid);
  stage_tile(Bb, 512, &Bl[0][0], tid);
  __syncthreads();

  const int wr = wid >> 1, wc = wid & 1;

  for (int kb = 0; kb < 8; ++kb){
    const int cur = kb & 1;
    if (kb < 7){
      stage_tile(Ab + (kb + 1) * 64, 512, &Al[cur ^ 1][0], tid);
      stage_tile(Bb + (kb + 1) * 64, 512, &Bl[cur ^ 1][0], tid);
    }
    #pragma unroll
    for (int ks = 0; ks < 2; ++ks){
      bf16x8 af[4], bf[4];
      #pragma unroll
      for (int i = 0; i < 4; ++i) af[i] = frag_at(&Al[cur][0], wr * 64 + i * 16 + lr, ks * 4 + lg);
      #pragma unroll
      for (int j = 0; j < 4; ++j) bf[j] = frag_at(&Bl[cur][0], wc * 64 + j * 16 + lr, ks * 4 + lg);
      #pragma unroll
      for (int i = 0; i < 4; ++i)
        #pragma unroll
        for (int j = 0; j < 4; ++j)
          acc[i][j] = __builtin_amdgcn_mfma_f32_16x16x32_bf16(af[i], bf[j], acc[i][j], 0, 0, 0);
    }
    __syncthreads();
  }

  #pragma unroll
  for (int j = 0; j < 4; ++j){
    int col = cb * 128 + wc * 64 + j * 16 + lr;
    #pragma unroll
    for (int i = 0; i < 4; ++i){
      int row0 = rb * 128 + wr * 64 + i * 16 + lg * 4;
      #pragma unroll
      for (int r = 0; r < 4; ++r){
        _Float16 h = (_Float16)acc[i][j][r];
        Cb[((size_t)(row0 + r) << 10) + col] = __builtin_bit_cast(unsigned short, h);
      }
    }
  }
}

// ---------- softmax rows in place: fp16 S (+v col bias) -> bf16 P = w[t]*exp/l ----------
__global__ __launch_bounds__(256)
void k_softmax(unsigned short* __restrict__ S, const float* __restrict__ vcol,
               const float* __restrict__ tfw, int bt0){
  const int wid = threadIdx.x >> 6, l = threadIdx.x & 63;
  const size_t row = (size_t)blockIdx.x * 4 + wid;
  const int bt = bt0 + (int)(row >> 10);
  const int t = bt % 3;
  float t0 = tfw[0], t1 = tfw[1], t2 = tfw[2];
  float tm = fmaxf(t0, fmaxf(t1, t2));
  float e0 = __expf(t0 - tm), e1 = __expf(t1 - tm), e2 = __expf(t2 - tm);
  float w = (t == 0 ? e0 : (t == 1 ? e1 : e2)) / (e0 + e1 + e2);

  const float* vr = vcol + ((size_t)bt << 10) + l * 16;
  unsigned short* rp = S + (row << 10) + l * 16;
  u16x8 a = *(const u16x8*)rp;
  u16x8 b = *(const u16x8*)(rp + 8);
  f32x4 va0 = *(const f32x4*)(vr), va1 = *(const f32x4*)(vr + 4);
  f32x4 va2 = *(const f32x4*)(vr + 8), va3 = *(const f32x4*)(vr + 12);
  float x[16];
  #pragma unroll
  for (int j = 0; j < 8; ++j){
    x[j]     = (float)__builtin_bit_cast(_Float16, (unsigned short)a[j]);
    x[8 + j] = (float)__builtin_bit_cast(_Float16, (unsigned short)b[j]);
  }
  x[0] += va0[0]; x[1] += va0[1]; x[2]  += va0[2]; x[3]  += va0[3];
  x[4] += va1[0]; x[5] += va1[1]; x[6]  += va1[2]; x[7]  += va1[3];
  x[8] += va2[0]; x[9] += va2[1]; x[10] += va2[2]; x[11] += va2[3];
  x[12]+= va3[0]; x[13]+= va3[1]; x[14] += va3[2]; x[15] += va3[3];
  float m = x[0];
  #pragma unroll
  for (int j = 1; j < 16; ++j) m = fmaxf(m, x[j]);
  m = fmaxf(m, __shfl_xor(m, 1));
  m = fmaxf(m, __shfl_xor(m, 2));
  m = fmaxf(m, __shfl_xor(m, 4));
  m = fmaxf(m, __shfl_xor(m, 8));
  m = fmaxf(m, __shfl_xor(m, 16));
  m = fmaxf(m, __shfl_xor(m, 32));
  float s = 0.f;
  #pragma unroll
  for (int j = 0; j < 16; ++j){ x[j] = __expf(x[j] - m); s += x[j]; }
  s += __shfl_xor(s, 1);
  s += __shfl_xor(s, 2);
  s += __shfl_xor(s, 4);
  s += __shfl_xor(s, 8);
  s += __shfl_xor(s, 16);
  s += __shfl_xor(s, 32);
  float sc = w / s;
  u16x8 oa, ob;
  #pragma unroll
  for (int j = 0; j < 8; ++j){
    oa[j] = f2bf(x[j] * sc);
    ob[j] = f2bf(x[8 + j] * sc);
  }
  *(u16x8*)rp = oa;
  *(u16x8*)(rp + 8) = ob;
}

// ---------- out[b] = sum_t P[b,t] * V[b,t], f32 out. grid = nb*32, XCD-chunked. ----------
__global__ __launch_bounds__(256, 2)
void k_gemm_pv(const unsigned short* __restrict__ P, const unsigned short* __restrict__ Vt,
               float* __restrict__ out, int b0){
  __shared__ __align__(16) unsigned short Al[2][8192];
  __shared__ __align__(16) unsigned short Bl[2][8192];
  const int tid = threadIdx.x;
  const int l  = tid & 63;
  const int wid = tid >> 6;
  const int lr = l & 15;
  const int lg = l >> 4;
  const int cpx = gridDim.x >> 3;
  const int wg = (blockIdx.x & 7) * cpx + (blockIdx.x >> 3);
  const int bl = wg >> 5;              // local b
  const int b = b0 + bl;
  const int tile = wg & 31;
  const int rb = tile >> 2, cb = tile & 3;

  const f32x4 zero4 = {0.f, 0.f, 0.f, 0.f};
  f32x4 acc[4][4];
  #pragma unroll
  for (int i = 0; i < 4; ++i)
    #pragma unroll
    for (int j = 0; j < 4; ++j) acc[i][j] = zero4;

  {
    const unsigned short* Ab = P  + ((size_t)(bl * 3) << 20) + (size_t)rb * 128 * 1024;
    const unsigned short* Bb = Vt + ((size_t)(b * 3) << 19) + (size_t)cb * 128 * 1024;
    stage_tile(Ab, 1024, &Al[0][0], tid);
    stage_tile(Bb, 1024, &Bl[0][0], tid);
  }
  __syncthreads();

  const int wr = wid >> 1, wc = wid & 1;

  #pragma unroll 2
  for (int kb = 0; kb < 48; ++kb){
    const int cur = kb & 1;
    if (kb < 47){
      int kn = kb + 1;
      int t = kn >> 4, kk = kn & 15;
      const unsigned short* Ab = P  + ((size_t)(bl * 3 + t) << 20) + (size_t)rb * 128 * 1024 + kk * 64;
      const unsigned short* Bb = Vt + ((size_t)(b * 3 + t) << 19) + (size_t)cb * 128 * 1024 + kk * 64;
      stage_tile(Ab, 1024, &Al[cur ^ 1][0], tid);
      stage_tile(Bb, 1024, &Bl[cur ^ 1][0], tid);
    }
    #pragma unroll
    for (int ks = 0; ks < 2; ++ks){
      bf16x8 af[4], bf[4];
      #pragma unroll
      for (int i = 0; i < 4; ++i) af[i] = frag_at(&Al[cur][0], wr * 64 + i * 16 + lr, ks * 4 + lg);
      #pragma unroll
      for (int j = 0; j < 4; ++j) bf[j] = frag_at(&Bl[cur][0], wc * 64 + j * 16 + lr, ks * 4 + lg);
      #pragma unroll
      for (int i = 0; i < 4; ++i)
        #pragma unroll
        for (int j = 0; j < 4; ++j)
          acc[i][j] = __builtin_amdgcn_mfma_f32_16x16x32_bf16(af[i], bf[j], acc[i][j], 0, 0, 0);
    }
    __syncthreads();
  }

  float* ob = out + ((size_t)b << 19);
  #pragma unroll
  for (int j = 0; j < 4; ++j){
    int col = cb * 128 + wc * 64 + j * 16 + lr;
    #pragma unroll
    for (int i = 0; i < 4; ++i){
      int row0 = rb * 128 + wr * 64 + i * 16 + lg * 4;
      #pragma unroll
      for (int r = 0; r < 4; ++r){
        ob[((size_t)(row0 + r) << 9) + col] = acc[i][j][r];
      }
    }
  }
}

extern "C" void kernel_launch(void* const* d_in, const int* in_sizes, int n_in,
                              void* d_out, int out_size, void* d_ws, size_t ws_size,
                              hipStream_t stream){
  (void)in_sizes; (void)n_in; (void)out_size;
  const float* f4h = (const float*)d_in[0];
  const float* f1d = (const float*)d_in[1];
  const float* f1w = (const float*)d_in[2];
  const float* Wq  = (const float*)d_in[3];
  const float* bq  = (const float*)d_in[4];
  const float* Wk  = (const float*)d_in[5];
  const float* bk  = (const float*)d_in[6];
  const float* Wv  = (const float*)d_in[7];
  const float* bv  = (const float*)d_in[8];
  const float* tfw = (const float*)d_in[9];
  (void)bk;  // row-constant in scores: cancels in softmax
  float* out = (float*)d_out;

  const size_t N48 = (size_t)48 * 1024 * 512;     // 25165824 elems
  unsigned short* Gb  = (unsigned short*)d_ws;
  unsigned short* Xb  = Gb + N48;
  unsigned short* Vt  = Xb + N48;
  float*          vcol = (float*)(Vt + N48);      // 49152 f32
  unsigned short* WqT = (unsigned short*)(vcol + 49152);
  unsigned short* WkT = WqT + 262144;
  unsigned short* Wv16= WkT + 262144;
  unsigned short* Mt  = Wv16 + 262144;
  unsigned short* Sb  = WqT;                      // S/P overlays weights region

  const float SC = 0.04419417382415922f;          // 1/sqrt(512)
  const size_t base = 3 * N48 * 2 + 49152 * 4;    // bytes before Sb
  const size_t s_full = (size_t)48 * 1024 * 1024 * 2;

  k_w1<<<8, 256, 0, stream>>>(Wk, bq, vcol);      // temp: w1 in vcol? NO -- separate
  // w1 lives in the last 2KB of the weights block (dead until conv uses it; Mt written later)
  // Simpler: reuse Mt region tail is unsafe (Mt written after conv_feat reads w1). Use a
  // dedicated slot right after Mt:
  float* w1 = (float*)(Mt + 262144);
  k_w1<<<8, 256, 0, stream>>>(Wk, bq, w1);
  k_conv_wt<<<128, 256, 0, stream>>>(Wq, Wk, WqT, WkT);
  k_conv_wv<<<128, 256, 0, stream>>>(Wv, Wv16);
  k_conv_feat<<<12288, 256, 0, stream>>>(f4h, f1d, f1w, w1, Xb, vcol);
  k_gemm_proj<0><<<16, 256, 0, stream>>>(WkT, WqT, nullptr, Mt, 512, SC);
  k_gemm_proj<0><<<1536, 256, 0, stream>>>(Xb, Mt, nullptr, Gb, 512, 1.0f);
  k_gemm_proj<1><<<1536, 256, 0, stream>>>(Wv16, Xb, bv, Vt, 49152, 1.0f);

  if (ws_size >= base + 2048 + s_full){
    // full-S path (Sb overlays weights incl. w1 -- all dead by now)
    k_gemm_qk<<<3072, 256, 0, stream>>>(Gb, Xb, Sb, 0);
    k_softmax<<<12288, 256, 0, stream>>>(Sb, vcol, tfw, 0);
    k_gemm_pv<<<512, 256, 0, stream>>>(Sb, Vt, out, 0);
  } else {
    for (int h = 0; h < 2; ++h){
      int bt0 = h * 24;
      k_gemm_qk<<<1536, 256, 0, stream>>>(Gb, Xb, Sb, bt0);
      k_softmax<<<6144, 256, 0, stream>>>(Sb, vcol, tfw, bt0);
      k_gemm_pv<<<256, 256, 0, stream>>>(Sb, Vt, out, h * 8);
    }
  }
}